// Round 2
// baseline (394.695 us; speedup 1.0000x reference)
//
#include <hip/hip_runtime.h>
#include <hip/hip_bf16.h>

#define NN 20000        // N_NODES
#define NE 640000       // N_EDGES
#define FEAT 416

// d_ws layout: int flag at byte 0 (1 = int32 layout, 2 = int64 layout),
// bb5 floats (NN*15) starting at byte 64.

__global__ __launch_bounds__(256) void prep_kernel(const float* __restrict__ bb,
                                                   const int* __restrict__ ei,
                                                   int* __restrict__ flag,
                                                   float* __restrict__ bb5) {
    int t = blockIdx.x * 256 + threadIdx.x;

    // dtype probe: if edge_index is int64, the high dword of each qword is 0
    // (values are in [0, 20000)). With int32 data these dwords are random
    // indices, P(all 64 == 0) ~ (1/20000)^64 ~ 0.
    if (blockIdx.x == 0 && threadIdx.x < 64) {
        int v = ei[2 * threadIdx.x + 1];
        unsigned long long m = __ballot(v != 0);
        if (threadIdx.x == 0) flag[0] = (m == 0ULL) ? 2 : 1;
    }

    if (t < NN) {
        const float* r = bb + (size_t)t * 12;
        float Nx = r[0], Ny = r[1], Nz = r[2];
        float CAx = r[3], CAy = r[4], CAz = r[5];
        float Cx = r[6], Cy = r[7], Cz = r[8];
        float Ox = r[9], Oy = r[10], Oz = r[11];
        float bx = CAx - Nx, by = CAy - Ny, bz = CAz - Nz;
        float cx = Cx - CAx, cy = Cy - CAy, cz = Cz - CAz;
        float ax = by * cz - bz * cy;
        float ay = bz * cx - bx * cz;
        float az = bx * cy - by * cx;
        float vx = -0.58273431f * ax + 0.56802827f * bx - 0.54067466f * cx + CAx;
        float vy = -0.58273431f * ay + 0.56802827f * by - 0.54067466f * cy + CAy;
        float vz = -0.58273431f * az + 0.56802827f * bz - 0.54067466f * cz + CAz;
        float* w = bb5 + (size_t)t * 15;
        w[0] = Nx;  w[1] = Ny;  w[2] = Nz;
        w[3] = CAx; w[4] = CAy; w[5] = CAz;
        w[6] = Cx;  w[7] = Cy;  w[8] = Cz;
        w[9] = Ox;  w[10] = Oy; w[11] = Oz;
        w[12] = vx; w[13] = vy; w[14] = vz;
    }
}

#define RBF_BLOCKS 250000   // NE*100/256 : one thread per float4 RBF chunk
#define POS_BLOCKS 40000    // NE*16/256  : one thread per positional scalar

__device__ __forceinline__ void load_idx(const int* __restrict__ ei, int sel, int e,
                                         int& dst, int& src) {
    if (sel == 2) {            // int64 layout: low dword of qword
        dst = ei[2 * e];
        src = ei[2 * (NE + e)];
    } else {                   // int32 layout
        dst = ei[e];
        src = ei[NE + e];
    }
}

__global__ __launch_bounds__(256) void edge_kernel(const int* __restrict__ ei,
                                                   const float* __restrict__ bb5,
                                                   const int* __restrict__ flag,
                                                   float* __restrict__ out) {
    const int sel = flag[0];

    if (blockIdx.x < RBF_BLOCKS) {
        int t = blockIdx.x * 256 + threadIdx.x;       // < NE*100 exactly
        int e = t / 100;
        int c = t - e * 100;                          // float4 chunk in RBF region
        int p = c >> 2;                               // pair index: i*5 + j
        int g = c & 3;                                // k-group (4 RBF centers)
        int i = p / 5;                                // src atom
        int j = p - i * 5;                            // dst atom
        int dst, src;
        load_idx(ei, sel, e, dst, src);
        const float* S = bb5 + src * 15 + i * 3;
        const float* D = bb5 + dst * 15 + j * 3;
        float dx = S[0] - D[0] + 1e-8f;
        float dy = S[1] - D[1] + 1e-8f;
        float dz = S[2] - D[2] + 1e-8f;
        float dist = sqrtf(dx * dx + dy * dy + dz * dz);
        // (dist - mu_k)/sigma = dist*0.8 - k*(20/15)*0.8 = dist*0.8 - k*(16/15)
        float a = dist * 0.8f;
        float4 r;
        float u;
        int k0 = 4 * g;
        u = a - (float)(k0 + 0) * (16.0f / 15.0f); r.x = __expf(-(u * u));
        u = a - (float)(k0 + 1) * (16.0f / 15.0f); r.y = __expf(-(u * u));
        u = a - (float)(k0 + 2) * (16.0f / 15.0f); r.z = __expf(-(u * u));
        u = a - (float)(k0 + 3) * (16.0f / 15.0f); r.w = __expf(-(u * u));
        // out as float4: edge stride = 104 chunks; RBF chunk c at offset c.
        reinterpret_cast<float4*>(out)[(size_t)e * 104 + c] = r;
    } else {
        int t2 = (blockIdx.x - RBF_BLOCKS) * 256 + threadIdx.x;  // < NE*16 exactly
        int e = t2 >> 4;
        int m = t2 & 15;
        int dst, src;
        load_idx(ei, sel, e, dst, src);
        float d = (float)(dst - src);
        // freq[q] = exp(-q * ln(10000)/8), q = m & 7
        float fr = __expf(-(float)(m & 7) * 1.1512925464970229f);
        float ang = d * fr;
        float s, c;
        sincosf(ang, &s, &c);                     // accurate path: |ang| up to 2e4 rad
        out[(size_t)e * FEAT + 400 + m] = (m < 8) ? c : s;
    }
}

extern "C" void kernel_launch(void* const* d_in, const int* in_sizes, int n_in,
                              void* d_out, int out_size, void* d_ws, size_t ws_size,
                              hipStream_t stream) {
    const float* bb = (const float*)d_in[0];
    const int* ei = (const int*)d_in[1];
    int* flag = (int*)d_ws;
    float* bb5 = (float*)((char*)d_ws + 64);
    float* out = (float*)d_out;

    hipLaunchKernelGGL(prep_kernel, dim3((NN + 255) / 256), dim3(256), 0, stream,
                       bb, ei, flag, bb5);
    hipLaunchKernelGGL(edge_kernel, dim3(RBF_BLOCKS + POS_BLOCKS), dim3(256), 0, stream,
                       ei, bb5, flag, out);
}

// Round 3
// 201.466 us; speedup vs baseline: 1.9591x; 1.9591x over previous
//
#include <hip/hip_runtime.h>
#include <hip/hip_bf16.h>

#define NN 20000        // N_NODES
#define NE 640000       // N_EDGES
#define FEAT 416
#define EPB 16          // edges per block
#define EDGE_BLOCKS (NE / EPB)   // 40000

// d_ws layout: int flag at byte 0 (1 = int32 layout, 2 = int64 layout),
// bb5 floats (NN*15) starting at byte 64.

__global__ __launch_bounds__(256) void prep_kernel(const float* __restrict__ bb,
                                                   const int* __restrict__ ei,
                                                   int* __restrict__ flag,
                                                   float* __restrict__ bb5) {
    int t = blockIdx.x * 256 + threadIdx.x;

    // dtype probe: if edge_index is int64, the high dword of each qword is 0
    // (values in [0, 20000)). With int32 data these are random indices,
    // P(all 64 == 0) ~ (1/20000)^64 ~ 0.
    if (blockIdx.x == 0 && threadIdx.x < 64) {
        int v = ei[2 * threadIdx.x + 1];
        unsigned long long m = __ballot(v != 0);
        if (threadIdx.x == 0) flag[0] = (m == 0ULL) ? 2 : 1;
    }

    if (t < NN) {
        const float* r = bb + (size_t)t * 12;
        float Nx = r[0], Ny = r[1], Nz = r[2];
        float CAx = r[3], CAy = r[4], CAz = r[5];
        float Cx = r[6], Cy = r[7], Cz = r[8];
        float Ox = r[9], Oy = r[10], Oz = r[11];
        float bx = CAx - Nx, by = CAy - Ny, bz = CAz - Nz;
        float cx = Cx - CAx, cy = Cy - CAy, cz = Cz - CAz;
        float ax = by * cz - bz * cy;
        float ay = bz * cx - bx * cz;
        float az = bx * cy - by * cx;
        float vx = -0.58273431f * ax + 0.56802827f * bx - 0.54067466f * cx + CAx;
        float vy = -0.58273431f * ay + 0.56802827f * by - 0.54067466f * cy + CAy;
        float vz = -0.58273431f * az + 0.56802827f * bz - 0.54067466f * cz + CAz;
        float* w = bb5 + (size_t)t * 15;
        w[0] = Nx;  w[1] = Ny;  w[2] = Nz;
        w[3] = CAx; w[4] = CAy; w[5] = CAz;
        w[6] = Cx;  w[7] = Cy;  w[8] = Cz;
        w[9] = Ox;  w[10] = Oy; w[11] = Oz;
        w[12] = vx; w[13] = vy; w[14] = vz;
    }
}

__device__ __forceinline__ void load_idx(const int* __restrict__ ei, int sel, int e,
                                         int& dst, int& src) {
    if (sel == 2) {            // int64 layout: low dword of qword
        dst = ei[2 * e];
        src = ei[2 * (NE + e)];
    } else {                   // int32 layout
        dst = ei[e];
        src = ei[NE + e];
    }
}

__global__ __launch_bounds__(256) void edge_kernel(const int* __restrict__ ei,
                                                   const float* __restrict__ bb5,
                                                   const int* __restrict__ flag,
                                                   float* __restrict__ out) {
    __shared__ float dist[EPB * 25];   // pre-scaled by 0.8 (= 1/sigma)
    __shared__ int sidx[EPB * 2];      // (dst, src) per edge

    const int tid = threadIdx.x;
    const int e0 = blockIdx.x * EPB;

    if (tid < EPB) {
        int dst, src;
        load_idx(ei, flag[0], e0 + tid, dst, src);
        sidx[tid * 2] = dst;
        sidx[tid * 2 + 1] = src;
    }
    __syncthreads();

    // ---- Phase A: 400 distances (one per (edge, atom-pair)), staged in LDS
    for (int item = tid; item < EPB * 25; item += 256) {
        int s = item / 25;
        int p = item - s * 25;
        int i = p / 5;                 // src atom
        int j = p - i * 5;             // dst atom
        int dst = sidx[s * 2], src = sidx[s * 2 + 1];
        const float* S = bb5 + src * 15 + i * 3;
        const float* D = bb5 + dst * 15 + j * 3;
        float dx = S[0] - D[0] + 1e-8f;
        float dy = S[1] - D[1] + 1e-8f;
        float dz = S[2] - D[2] + 1e-8f;
        dist[item] = sqrtf(dx * dx + dy * dy + dz * dz) * 0.8f;
    }

    float4* out4 = reinterpret_cast<float4*>(out) + (size_t)e0 * 104;

    // ---- Phase C: positional embeddings (threads 0..63), exact-style reduction
    // angle = (float)(dst-src) * freq_f32  (bit-matches reference product);
    // reduce in double to revolutions, then raw v_sin/v_cos.
    if (tid < EPB * 4) {
        int s = tid >> 2;
        int g = tid & 3;                       // output chunk: 0,1=cos(f 0-3,4-7); 2,3=sin
        int dst = sidx[s * 2], src = sidx[s * 2 + 1];
        float d = (float)(dst - src);
        int fb = (g & 1) * 4;
        bool issin = (g >= 2);
        float v[4];
#pragma unroll
        for (int k = 0; k < 4; ++k) {
            int f = fb + k;
            float freq = expf(-(float)f * (float)(9.210340371976184 / 8.0)); // accurate
            float angle = d * freq;                       // f32, matches ref
            double t = (double)angle * 0.15915494309189535; // 1/(2*pi)
            double r = t - rint(t);                       // |r| <= 0.5 revolutions
            float rf = (float)r;
            float val;
            if (issin) {
                asm("v_sin_f32 %0, %1" : "=v"(val) : "v"(rf));
            } else {
                asm("v_cos_f32 %0, %1" : "=v"(val) : "v"(rf));
            }
            v[k] = val;
        }
        float4 r4 = make_float4(v[0], v[1], v[2], v[3]);
        out4[s * 104 + 100 + g] = r4;
    }
    __syncthreads();

    // ---- Phase B: RBF chunks, one float4 per thread, fully coalesced
    for (int item = tid; item < EPB * 100; item += 256) {
        int s = item / 100;
        int c = item - s * 100;        // chunk within edge's RBF region
        int p = c >> 2;                // pair index
        int g = c & 3;                 // 4-center group
        float a = dist[s * 25 + p];    // broadcast read (4 lanes share)
        int k0 = g * 4;
        float4 r;
        float u;
        u = a - (float)(k0 + 0) * (16.0f / 15.0f); r.x = __expf(-(u * u));
        u = a - (float)(k0 + 1) * (16.0f / 15.0f); r.y = __expf(-(u * u));
        u = a - (float)(k0 + 2) * (16.0f / 15.0f); r.z = __expf(-(u * u));
        u = a - (float)(k0 + 3) * (16.0f / 15.0f); r.w = __expf(-(u * u));
        out4[s * 104 + c] = r;
    }
}

extern "C" void kernel_launch(void* const* d_in, const int* in_sizes, int n_in,
                              void* d_out, int out_size, void* d_ws, size_t ws_size,
                              hipStream_t stream) {
    const float* bb = (const float*)d_in[0];
    const int* ei = (const int*)d_in[1];
    int* flag = (int*)d_ws;
    float* bb5 = (float*)((char*)d_ws + 64);
    float* out = (float*)d_out;

    hipLaunchKernelGGL(prep_kernel, dim3((NN + 255) / 256), dim3(256), 0, stream,
                       bb, ei, flag, bb5);
    hipLaunchKernelGGL(edge_kernel, dim3(EDGE_BLOCKS), dim3(256), 0, stream,
                       ei, bb5, flag, out);
}